// Round 8
// baseline (167.700 us; speedup 1.0000x reference)
//
#include <hip/hip_runtime.h>

// Problem constants (from reference)
#define NN 4096
#define CC 128
#define II 9
#define DD 9
#define EE 10
#define PP3 23
#define PP2 5
#define PP1 3
// symmetric monomial counts over 9 vars
#define F3 165   // i<=j<=k
#define F2 45    // i<=j
#define F1 9
#define FTOT (F3 + F2 + F1)  // 219
#define FPAD 224             // padded K (7 x 32)
#define NKT 7                // K-tiles of 32

// workspace layout (bytes)
#define SU3_ELEMS (F3 * PP3 * DD)              // 34155 floats
#define SU2_ELEMS (F2 * PP2 * DD)              // 2025 floats
#define SU3_OFF 0
#define SU2_OFF (SU3_OFF + SU3_ELEMS * 4)
#define CUR_OFF (SU2_OFF + SU2_ELEMS * 4)
#define LIST_OFF (CUR_OFF + 64)                // 16 ints + pad
#define WG16_OFF (LIST_OFF + NN * EE * 4)      // f16 W images: E*C*16*224*2 = 9.2 MB

// LDS monomial tile: 128 node rows x 122 dwords (244 f16, 224 used)
#define MROW 122
#define NODES_PER_ITER 128

typedef _Float16 f16x8 __attribute__((ext_vector_type(8)));
typedef float f32x4 __attribute__((ext_vector_type(4)));

union LdsVec {
    struct { unsigned long long lo, hi; };
    f16x8 v;
};

static __device__ __forceinline__ unsigned pack2(float a, float b) {
    _Float16 ha = (_Float16)a, hb = (_Float16)b;
    unsigned short ua = __builtin_bit_cast(unsigned short, ha);
    unsigned short ub = __builtin_bit_cast(unsigned short, hb);
    return (unsigned)ua | ((unsigned)ub << 16);
}

__global__ void zero_cursors_kernel(int* cursors) {
    if (threadIdx.x < 16) cursors[threadIdx.x] = 0;
}

// Atomic append bucketing. List ORDER is nondeterministic, but each node's
// result is a fixed-order dot product independent of its list slot, so
// d_out is bit-deterministic.
__global__ void bucket_kernel(const int* __restrict__ indices,
                              int* __restrict__ cursors,
                              int* __restrict__ lists) {
    int b = blockIdx.x * blockDim.x + threadIdx.x;
    if (b < NN) {
        int e = indices[b];
        int slot = atomicAdd(&cursors[e], 1);
        lists[e * NN + slot] = b;
    }
}

// Symmetrize u3 over (i,j,k) and u2 over (i,j) into monomial-indexed tensors.
__global__ void sym_u_kernel(const float* __restrict__ u3,
                             const float* __restrict__ u2,
                             float* __restrict__ su3,
                             float* __restrict__ su2) {
    int gid = blockIdx.x * blockDim.x + threadIdx.x;
    if (gid < F3 * PP3) {
        int t = gid / PP3, p = gid % PP3;
        int I0 = 0, J0 = 0, K0 = 0, tt = 0;
        for (int i = 0; i < 9; i++)
            for (int j = i; j < 9; j++)
                for (int k = j; k < 9; k++) {
                    if (tt == t) { I0 = i; J0 = j; K0 = k; }
                    tt++;
                }
        int a[3] = {I0, J0, K0};
        const int ord[6][3] = {{0,1,2},{0,2,1},{1,0,2},{1,2,0},{2,0,1},{2,1,0}};
        int codes[6], pi[6], pj[6], pk[6];
        int np = 0;
        for (int q = 0; q < 6; q++) {
            int ii = a[ord[q][0]], jj = a[ord[q][1]], kk = a[ord[q][2]];
            int code = (ii * 9 + jj) * 9 + kk;
            bool seen = false;
            for (int r = 0; r < np; r++) if (codes[r] == code) seen = true;
            if (!seen) { codes[np] = code; pi[np] = ii; pj[np] = jj; pk[np] = kk; np++; }
        }
        for (int d = 0; d < 9; d++) {
            float s = 0.f;
            for (int q = 0; q < np; q++)
                s += u3[((((d * 9 + pi[q]) * 9 + pj[q]) * 9 + pk[q]) * PP3) + p];
            su3[(t * PP3 + p) * 9 + d] = s;
        }
    } else if (gid < F3 * PP3 + F2 * PP2) {
        int r = gid - F3 * PP3;
        int t = r / PP2, p = r % PP2;
        int I0 = 0, J0 = 0, tt = 0;
        for (int i = 0; i < 9; i++)
            for (int j = i; j < 9; j++) {
                if (tt == t) { I0 = i; J0 = j; }
                tt++;
            }
        for (int d = 0; d < 9; d++) {
            float s = u2[(((d * 9 + I0) * 9 + J0) * PP2) + p];
            if (I0 != J0) s += u2[(((d * 9 + J0) * 9 + I0) * PP2) + p];
            su2[(t * PP2 + p) * 9 + d] = s;
        }
    }
}

// Precompute per-(e,c) f16 weight image in MFMA-B-friendly layout:
// Wg16[e][c][d (16, col)][f (224, K)] as packed f16 pairs (112 dwords per d).
__global__ __launch_bounds__(128) void wprep16_kernel(
    const float* __restrict__ su3,
    const float* __restrict__ su2,
    const float* __restrict__ u1,
    const float* __restrict__ w3,
    const float* __restrict__ w2,
    const float* __restrict__ w1,
    unsigned* __restrict__ Wg16)
{
    const int c = blockIdx.x;
    const int e = blockIdx.y;
    unsigned* dst = Wg16 + (size_t)(e * CC + c) * (16 * FPAD / 2);
    for (int idx = threadIdx.x; idx < 16 * FPAD / 2; idx += blockDim.x) {
        const int d = idx / (FPAD / 2);
        const int q = idx % (FPAD / 2);
        float v[2] = {0.f, 0.f};
        if (d < 9) {
            #pragma unroll
            for (int h = 0; h < 2; h++) {
                const int f = 2 * q + h;
                float s = 0.f;
                if (f < F3) {
                    for (int p = 0; p < PP3; p++)
                        s += su3[(f * PP3 + p) * 9 + d] * w3[(e * PP3 + p) * CC + c];
                } else if (f < F3 + F2) {
                    int t = f - F3;
                    for (int p = 0; p < PP2; p++)
                        s += su2[(t * PP2 + p) * 9 + d] * w2[(e * PP2 + p) * CC + c];
                } else if (f < FTOT) {
                    int i = f - F3 - F2;
                    for (int p = 0; p < PP1; p++)
                        s += u1[(d * 9 + i) * PP1 + p] * w1[(e * PP1 + p) * CC + c];
                }
                v[h] = s;
            }
        }
        dst[idx] = pack2(v[0], v[1]);
    }
}

// Main MFMA kernel: grid (C, E), 256 threads (4 waves).
// Per 128-node iteration:
//   phase 1: threads 0..127 compute their node's 219 monomials via a fully
//            static mul stream (no dynamic indexing, <=2 live temps) and
//            ds_write f16 pairs into M_lds[node][f].
//   phase 2: all 4 waves run 2 MFMA tiles each (16x16x32 f16, 7 K-tiles),
//            D[node][d] = sum_f M[node][f] * W[f][d], scatter f32 results.
__global__ __launch_bounds__(256, 2) void symcon_mfma_kernel(
    const float* __restrict__ x,
    const unsigned short* __restrict__ Wg16,
    const int* __restrict__ cursors,
    const int* __restrict__ lists,
    float* __restrict__ out)
{
    const int c = blockIdx.x;
    const int e = blockIdx.y;
    const int tid = threadIdx.x;
    const int lane = tid & 63;
    const int wid = tid >> 6;

    __shared__ __align__(16) unsigned sM[NODES_PER_ITER * MROW];

    // B fragments: lane holds B[k = t*32 + (lane>>4)*8 + j][col = lane&15]
    // = Wg16 image [col][k..k+8) -> one 16B load per K-tile.
    const int bcol = lane & 15;
    const int bg = lane >> 4;
    f16x8 bfrag[NKT];
    {
        const unsigned short* wp = Wg16 + (size_t)(e * CC + c) * (16 * FPAD);
        #pragma unroll
        for (int t = 0; t < NKT; t++)
            bfrag[t] = *reinterpret_cast<const f16x8*>(wp + bcol * FPAD + t * 32 + bg * 8);
    }

    const int cnt = cursors[e];

    for (int base = 0; base < cnt; base += NODES_PER_ITER) {
        // ---- phase 1: monomials ----
        if (tid < NODES_PER_ITER) {
            const int n = base + tid;
            const bool valid = (n < cnt);
            const int b = valid ? lists[e * NN + n] : 0;
            const float* xr = x + ((size_t)b * CC + c) * II;
            float xv[9];
            #pragma unroll
            for (int q = 0; q < 9; q++) xv[q] = valid ? xr[q] : 0.f;

            const int wb = tid * MROW;
            float pend = 0.f;
            int f = 0;
            // EMIT streams pairs straight to LDS; f folds to constants
            #define EMIT(mval) { float _m = (mval);                         \
                if (f & 1) sM[wb + (f >> 1)] = pack2(pend, _m);             \
                else pend = _m;                                             \
                f++; }
            #pragma unroll
            for (int i = 0; i < 9; i++) {
                #pragma unroll
                for (int j = i; j < 9; j++) {
                    float xij = xv[i] * xv[j];
                    #pragma unroll
                    for (int k = j; k < 9; k++) EMIT(xij * xv[k])
                }
            }
            #pragma unroll
            for (int i = 0; i < 9; i++) {
                #pragma unroll
                for (int j = i; j < 9; j++) EMIT(xv[i] * xv[j])
            }
            #pragma unroll
            for (int i = 0; i < 9; i++) EMIT(xv[i])
            // f == 219 here (odd): flush last pair, zero-pad f 220..223
            sM[wb + 109] = pack2(pend, 0.f);
            sM[wb + 110] = 0u;
            sM[wb + 111] = 0u;
            #undef EMIT
        }
        __syncthreads();

        // ---- phase 2: MFMA (2 tiles per wave) ----
        #pragma unroll
        for (int tt = 0; tt < 2; tt++) {
            const int T = wid * 2 + tt;
            // A read: lane holds A[row = lane&15][k = t*32 + (lane>>4)*8 + j]
            const int arow = T * 16 + (lane & 15);
            const int abase = arow * MROW + bg * 4;
            f32x4 acc = {0.f, 0.f, 0.f, 0.f};
            #pragma unroll
            for (int t = 0; t < NKT; t++) {
                LdsVec u;
                u.lo = *reinterpret_cast<const unsigned long long*>(&sM[abase + t * 16]);
                u.hi = *reinterpret_cast<const unsigned long long*>(&sM[abase + t * 16 + 2]);
                acc = __builtin_amdgcn_mfma_f32_16x16x32_f16(u.v, bfrag[t], acc, 0, 0, 0);
            }
            // C/D: col = lane&15, row = (lane>>4)*4 + p  [verified layout]
            if (bcol < 9) {
                #pragma unroll
                for (int p = 0; p < 4; p++) {
                    const int s = T * 16 + bg * 4 + p;
                    const int n = base + s;
                    if (n < cnt) {
                        const int b = lists[e * NN + n];
                        out[((size_t)b * CC + c) * DD + bcol] = acc[p];
                    }
                }
            }
        }
        __syncthreads();
    }
}

extern "C" void kernel_launch(void* const* d_in, const int* in_sizes, int n_in,
                              void* d_out, int out_size, void* d_ws, size_t ws_size,
                              hipStream_t stream) {
    const float* x   = (const float*)d_in[0];
    const int* indices = (const int*)d_in[1];
    const float* u3  = (const float*)d_in[2];
    const float* u2  = (const float*)d_in[3];
    const float* u1  = (const float*)d_in[4];
    const float* w3  = (const float*)d_in[5];
    const float* w2  = (const float*)d_in[6];
    const float* w1  = (const float*)d_in[7];
    float* out = (float*)d_out;

    char* ws = (char*)d_ws;
    float* su3 = (float*)(ws + SU3_OFF);
    float* su2 = (float*)(ws + SU2_OFF);
    int* cursors = (int*)(ws + CUR_OFF);
    int* lists = (int*)(ws + LIST_OFF);
    unsigned* Wg16 = (unsigned*)(ws + WG16_OFF);

    hipLaunchKernelGGL(zero_cursors_kernel, dim3(1), dim3(64), 0, stream, cursors);
    hipLaunchKernelGGL(bucket_kernel, dim3((NN + 255) / 256), dim3(256), 0, stream,
                       indices, cursors, lists);
    hipLaunchKernelGGL(sym_u_kernel, dim3((F3 * PP3 + F2 * PP2 + 255) / 256), dim3(256),
                       0, stream, u3, u2, su3, su2);
    hipLaunchKernelGGL(wprep16_kernel, dim3(CC, EE), dim3(128), 0, stream,
                       su3, su2, u1, w3, w2, w1, Wg16);
    hipLaunchKernelGGL(symcon_mfma_kernel, dim3(CC, EE), dim3(256), 0, stream,
                       x, (const unsigned short*)Wg16, cursors, lists, out);
}

// Round 9
// 127.245 us; speedup vs baseline: 1.3179x; 1.3179x over previous
//
#include <hip/hip_runtime.h>

// Problem constants (from reference)
#define NN 4096
#define CC 128
#define II 9
#define DD 9
#define EE 10
#define PP3 23
#define PP2 5
#define PP1 3
// symmetric monomial counts over 9 vars
#define F3 165   // i<=j<=k
#define F2 45    // i<=j
#define F1 9
#define FTOT (F3 + F2 + F1)  // 219
#define FPAD 224             // padded K (7 x 32)
#define NKT 7                // K-tiles of 32

// workspace layout (bytes)
#define SU3_ELEMS (F3 * PP3 * DD)              // 34155 floats
#define SU2_ELEMS (F2 * PP2 * DD)              // 2025 floats
#define SU3_OFF 0
#define SU2_OFF (SU3_OFF + SU3_ELEMS * 4)
#define CUR_OFF (SU2_OFF + SU2_ELEMS * 4)
#define LIST_OFF (CUR_OFF + 64)                // 16 ints + pad
#define WG16_OFF (LIST_OFF + NN * EE * 4)      // f16 W images: E*C*16*224*2 = 9.2 MB

// LDS monomial tile: 128 node rows x 122 dwords (244 f16, 224 used)
#define MROW 122
#define NODES_PER_ITER 128

typedef _Float16 f16x8 __attribute__((ext_vector_type(8)));
typedef float f32x4 __attribute__((ext_vector_type(4)));

union LdsVec {
    struct { unsigned long long lo, hi; };
    f16x8 v;
};

static __device__ __forceinline__ unsigned pack2(float a, float b) {
    _Float16 ha = (_Float16)a, hb = (_Float16)b;
    unsigned short ua = __builtin_bit_cast(unsigned short, ha);
    unsigned short ub = __builtin_bit_cast(unsigned short, hb);
    return (unsigned)ua | ((unsigned)ub << 16);
}

static __device__ __forceinline__ unsigned short h16(float a) {
    _Float16 ha = (_Float16)a;
    return __builtin_bit_cast(unsigned short, ha);
}

__global__ void zero_cursors_kernel(int* cursors) {
    if (threadIdx.x < 16) cursors[threadIdx.x] = 0;
}

// Atomic append bucketing. List ORDER is nondeterministic, but each node's
// result is a fixed-order dot product independent of its list slot, so
// d_out is bit-deterministic.
__global__ void bucket_kernel(const int* __restrict__ indices,
                              int* __restrict__ cursors,
                              int* __restrict__ lists) {
    int b = blockIdx.x * blockDim.x + threadIdx.x;
    if (b < NN) {
        int e = indices[b];
        int slot = atomicAdd(&cursors[e], 1);
        lists[e * NN + slot] = b;
    }
}

// Symmetrize u3 over (i,j,k) and u2 over (i,j) into monomial-indexed tensors.
// Unranking is early-exit O(45) (round-9: was O(729) full scan).
__global__ void sym_u_kernel(const float* __restrict__ u3,
                             const float* __restrict__ u2,
                             float* __restrict__ su3,
                             float* __restrict__ su2) {
    int gid = blockIdx.x * blockDim.x + threadIdx.x;
    if (gid < F3 * PP3) {
        int t = gid / PP3, p = gid % PP3;
        int I0 = 0, J0 = 0, K0 = 0;
        {
            int rem = t;
            bool found = false;
            for (int i = 0; i < 9 && !found; i++)
                for (int j = i; j < 9 && !found; j++) {
                    int cnt = 9 - j;
                    if (rem < cnt) { I0 = i; J0 = j; K0 = j + rem; found = true; }
                    else rem -= cnt;
                }
        }
        int a[3] = {I0, J0, K0};
        const int ord[6][3] = {{0,1,2},{0,2,1},{1,0,2},{1,2,0},{2,0,1},{2,1,0}};
        int codes[6], pi[6], pj[6], pk[6];
        int np = 0;
        for (int q = 0; q < 6; q++) {
            int ii = a[ord[q][0]], jj = a[ord[q][1]], kk = a[ord[q][2]];
            int code = (ii * 9 + jj) * 9 + kk;
            bool seen = false;
            for (int r = 0; r < np; r++) if (codes[r] == code) seen = true;
            if (!seen) { codes[np] = code; pi[np] = ii; pj[np] = jj; pk[np] = kk; np++; }
        }
        for (int d = 0; d < 9; d++) {
            float s = 0.f;
            for (int q = 0; q < np; q++)
                s += u3[((((d * 9 + pi[q]) * 9 + pj[q]) * 9 + pk[q]) * PP3) + p];
            su3[(t * PP3 + p) * 9 + d] = s;
        }
    } else if (gid < F3 * PP3 + F2 * PP2) {
        int r = gid - F3 * PP3;
        int t = r / PP2, p = r % PP2;
        int I0 = 0, J0 = 0;
        {
            int rem = t;
            bool found = false;
            for (int i = 0; i < 9 && !found; i++) {
                int cnt = 9 - i;
                if (rem < cnt) { I0 = i; J0 = i + rem; found = true; }
                else rem -= cnt;
            }
        }
        for (int d = 0; d < 9; d++) {
            float s = u2[(((d * 9 + I0) * 9 + J0) * PP2) + p];
            if (I0 != J0) s += u2[(((d * 9 + J0) * 9 + I0) * PP2) + p];
            su2[(t * PP2 + p) * 9 + d] = s;
        }
    }
}

// Precompute per-(e,c) f16 weight image, layout [d (16, col)][f (224, K)].
// Round-9 rewrite: one thread per f — su3 row reads become float4 vector
// loads (69 independent loads vs 644 scalars), w-weights are block-uniform
// (SGPR), output staged in LDS and copied out fully coalesced.
__global__ __launch_bounds__(256) void wprep16_kernel(
    const float* __restrict__ su3,
    const float* __restrict__ su2,
    const float* __restrict__ u1,
    const float* __restrict__ w3,
    const float* __restrict__ w2,
    const float* __restrict__ w1,
    unsigned* __restrict__ Wg16)
{
    const int c = blockIdx.x;
    const int e = blockIdx.y;
    const int tid = threadIdx.x;

    __shared__ unsigned short sImg[16 * FPAD];   // 7 KB f16 image [d][f]
    unsigned* sImgW = reinterpret_cast<unsigned*>(sImg);
    for (int q = tid; q < 16 * FPAD / 2; q += 256) sImgW[q] = 0u;
    __syncthreads();

    if (tid < FTOT) {
        float acc[9];
        #pragma unroll
        for (int d = 0; d < 9; d++) acc[d] = 0.f;

        if (tid < F3) {
            const float* sp = su3 + (size_t)tid * PP3 * 9;
            #pragma unroll
            for (int p = 0; p < PP3; p++) {
                const float wv = w3[(e * PP3 + p) * CC + c];     // uniform -> SGPR
                const float4 a = *reinterpret_cast<const float4*>(sp + p * 9);
                const float4 b = *reinterpret_cast<const float4*>(sp + p * 9 + 4);
                const float g = sp[p * 9 + 8];
                acc[0] += wv * a.x; acc[1] += wv * a.y; acc[2] += wv * a.z; acc[3] += wv * a.w;
                acc[4] += wv * b.x; acc[5] += wv * b.y; acc[6] += wv * b.z; acc[7] += wv * b.w;
                acc[8] += wv * g;
            }
        } else if (tid < F3 + F2) {
            const float* sp = su2 + (size_t)(tid - F3) * PP2 * 9;
            #pragma unroll
            for (int p = 0; p < PP2; p++) {
                const float wv = w2[(e * PP2 + p) * CC + c];
                const float4 a = *reinterpret_cast<const float4*>(sp + p * 9);
                const float4 b = *reinterpret_cast<const float4*>(sp + p * 9 + 4);
                const float g = sp[p * 9 + 8];
                acc[0] += wv * a.x; acc[1] += wv * a.y; acc[2] += wv * a.z; acc[3] += wv * a.w;
                acc[4] += wv * b.x; acc[5] += wv * b.y; acc[6] += wv * b.z; acc[7] += wv * b.w;
                acc[8] += wv * g;
            }
        } else {
            const int i = tid - F3 - F2;
            #pragma unroll
            for (int p = 0; p < PP1; p++) {
                const float wv = w1[(e * PP1 + p) * CC + c];
                #pragma unroll
                for (int d = 0; d < 9; d++)
                    acc[d] += wv * u1[(d * 9 + i) * PP1 + p];
            }
        }
        #pragma unroll
        for (int d = 0; d < 9; d++)
            sImg[d * FPAD + tid] = h16(acc[d]);
    }
    __syncthreads();

    unsigned* dst = Wg16 + (size_t)(e * CC + c) * (16 * FPAD / 2);
    for (int q = tid; q < 16 * FPAD / 2; q += 256) dst[q] = sImgW[q];
}

// Main MFMA kernel: grid (C, E), 256 threads (4 waves).
// Per 128-node iteration:
//   phase 1: threads 0..127 compute their node's 219 monomials via a fully
//            static mul stream (no dynamic indexing, <=2 live temps) and
//            ds_write f16 pairs into M_lds[node][f].
//   phase 2: all 4 waves run 2 MFMA tiles each (16x16x32 f16, 7 K-tiles),
//            D[node][d] = sum_f M[node][f] * W[f][d], scatter f32 results.
__global__ __launch_bounds__(256, 2) void symcon_mfma_kernel(
    const float* __restrict__ x,
    const unsigned short* __restrict__ Wg16,
    const int* __restrict__ cursors,
    const int* __restrict__ lists,
    float* __restrict__ out)
{
    const int c = blockIdx.x;
    const int e = blockIdx.y;
    const int tid = threadIdx.x;
    const int lane = tid & 63;
    const int wid = tid >> 6;

    __shared__ __align__(16) unsigned sM[NODES_PER_ITER * MROW];

    // B fragments: lane holds B[k = t*32 + (lane>>4)*8 + j][col = lane&15]
    // = Wg16 image [col][k..k+8) -> one 16B load per K-tile.
    const int bcol = lane & 15;
    const int bg = lane >> 4;
    f16x8 bfrag[NKT];
    {
        const unsigned short* wp = Wg16 + (size_t)(e * CC + c) * (16 * FPAD);
        #pragma unroll
        for (int t = 0; t < NKT; t++)
            bfrag[t] = *reinterpret_cast<const f16x8*>(wp + bcol * FPAD + t * 32 + bg * 8);
    }

    const int cnt = cursors[e];

    for (int base = 0; base < cnt; base += NODES_PER_ITER) {
        // ---- phase 1: monomials ----
        if (tid < NODES_PER_ITER) {
            const int n = base + tid;
            const bool valid = (n < cnt);
            const int b = valid ? lists[e * NN + n] : 0;
            const float* xr = x + ((size_t)b * CC + c) * II;
            float xv[9];
            #pragma unroll
            for (int q = 0; q < 9; q++) xv[q] = valid ? xr[q] : 0.f;

            const int wb = tid * MROW;
            float pend = 0.f;
            int f = 0;
            // EMIT streams pairs straight to LDS; f folds to constants
            #define EMIT(mval) { float _m = (mval);                         \
                if (f & 1) sM[wb + (f >> 1)] = pack2(pend, _m);             \
                else pend = _m;                                             \
                f++; }
            #pragma unroll
            for (int i = 0; i < 9; i++) {
                #pragma unroll
                for (int j = i; j < 9; j++) {
                    float xij = xv[i] * xv[j];
                    #pragma unroll
                    for (int k = j; k < 9; k++) EMIT(xij * xv[k])
                }
            }
            #pragma unroll
            for (int i = 0; i < 9; i++) {
                #pragma unroll
                for (int j = i; j < 9; j++) EMIT(xv[i] * xv[j])
            }
            #pragma unroll
            for (int i = 0; i < 9; i++) EMIT(xv[i])
            // f == 219 here (odd): flush last pair, zero-pad f 220..223
            sM[wb + 109] = pack2(pend, 0.f);
            sM[wb + 110] = 0u;
            sM[wb + 111] = 0u;
            #undef EMIT
        }
        __syncthreads();

        // ---- phase 2: MFMA (2 tiles per wave) ----
        #pragma unroll
        for (int tt = 0; tt < 2; tt++) {
            const int T = wid * 2 + tt;
            // A read: lane holds A[row = lane&15][k = t*32 + (lane>>4)*8 + j]
            const int arow = T * 16 + (lane & 15);
            const int abase = arow * MROW + bg * 4;
            f32x4 acc = {0.f, 0.f, 0.f, 0.f};
            #pragma unroll
            for (int t = 0; t < NKT; t++) {
                LdsVec u;
                u.lo = *reinterpret_cast<const unsigned long long*>(&sM[abase + t * 16]);
                u.hi = *reinterpret_cast<const unsigned long long*>(&sM[abase + t * 16 + 2]);
                acc = __builtin_amdgcn_mfma_f32_16x16x32_f16(u.v, bfrag[t], acc, 0, 0, 0);
            }
            // C/D: col = lane&15, row = (lane>>4)*4 + p  [verified layout]
            if (bcol < 9) {
                #pragma unroll
                for (int p = 0; p < 4; p++) {
                    const int s = T * 16 + bg * 4 + p;
                    const int n = base + s;
                    if (n < cnt) {
                        const int b = lists[e * NN + n];
                        out[((size_t)b * CC + c) * DD + bcol] = acc[p];
                    }
                }
            }
        }
        __syncthreads();
    }
}

extern "C" void kernel_launch(void* const* d_in, const int* in_sizes, int n_in,
                              void* d_out, int out_size, void* d_ws, size_t ws_size,
                              hipStream_t stream) {
    const float* x   = (const float*)d_in[0];
    const int* indices = (const int*)d_in[1];
    const float* u3  = (const float*)d_in[2];
    const float* u2  = (const float*)d_in[3];
    const float* u1  = (const float*)d_in[4];
    const float* w3  = (const float*)d_in[5];
    const float* w2  = (const float*)d_in[6];
    const float* w1  = (const float*)d_in[7];
    float* out = (float*)d_out;

    char* ws = (char*)d_ws;
    float* su3 = (float*)(ws + SU3_OFF);
    float* su2 = (float*)(ws + SU2_OFF);
    int* cursors = (int*)(ws + CUR_OFF);
    int* lists = (int*)(ws + LIST_OFF);
    unsigned* Wg16 = (unsigned*)(ws + WG16_OFF);

    hipLaunchKernelGGL(zero_cursors_kernel, dim3(1), dim3(64), 0, stream, cursors);
    hipLaunchKernelGGL(bucket_kernel, dim3((NN + 255) / 256), dim3(256), 0, stream,
                       indices, cursors, lists);
    hipLaunchKernelGGL(sym_u_kernel, dim3((F3 * PP3 + F2 * PP2 + 255) / 256), dim3(256),
                       0, stream, u3, u2, su3, su2);
    hipLaunchKernelGGL(wprep16_kernel, dim3(CC, EE), dim3(256), 0, stream,
                       su3, su2, u1, w3, w2, w1, Wg16);
    hipLaunchKernelGGL(symcon_mfma_kernel, dim3(CC, EE), dim3(256), 0, stream,
                       x, (const unsigned short*)Wg16, cursors, lists, out);
}

// Round 10
// 121.329 us; speedup vs baseline: 1.3822x; 1.0488x over previous
//
#include <hip/hip_runtime.h>

// Problem constants (from reference)
#define NN 4096
#define CC 128
#define II 9
#define DD 9
#define EE 10
#define PP3 23
#define PP2 5
#define PP1 3
// symmetric monomial counts over 9 vars
#define F3 165   // i<=j<=k
#define F2 45    // i<=j
#define F1 9
#define FTOT (F3 + F2 + F1)  // 219
#define FPAD 224             // padded K (7 x 32)
#define NKT 7                // K-tiles of 32

// workspace layout (bytes)
#define SU3_ELEMS (F3 * PP3 * DD)              // 34155 floats
#define SU2_ELEMS (F2 * PP2 * DD)              // 2025 floats
#define SU3_OFF 0
#define SU2_OFF (SU3_OFF + SU3_ELEMS * 4)
#define CUR_OFF (SU2_OFF + SU2_ELEMS * 4)
#define LIST_OFF (CUR_OFF + 64)                // 16 ints + pad
#define WG16_OFF (LIST_OFF + NN * EE * 4)      // f16 W images: E*C*16*224*2 = 9.2 MB

// LDS monomial tile: 64 node rows x 116 dwords (16B-aligned rows, 29.7 KB
// -> 5 blocks/CU; round-10: occupancy was the wall, not VALU)
#define MROW 116
#define NODES_PER_ITER 64

typedef _Float16 f16x8 __attribute__((ext_vector_type(8)));
typedef float f32x4 __attribute__((ext_vector_type(4)));

static __device__ __forceinline__ unsigned pack2(float a, float b) {
    _Float16 ha = (_Float16)a, hb = (_Float16)b;
    unsigned short ua = __builtin_bit_cast(unsigned short, ha);
    unsigned short ub = __builtin_bit_cast(unsigned short, hb);
    return (unsigned)ua | ((unsigned)ub << 16);
}

static __device__ __forceinline__ unsigned short h16(float a) {
    _Float16 ha = (_Float16)a;
    return __builtin_bit_cast(unsigned short, ha);
}

// Emit monomials f in [LO,HI) of the canonical 224-entry stream into LDS
// row wb. Fully unrolled; F and the guards fold at compile time, so each
// instantiation is a static mul/pack/ds_write stream (round-8 proven).
template<int LO, int HI>
static __device__ __forceinline__ void emit_mono(const float* xv, unsigned* sM, int wb) {
    float pend = 0.f;
    int F = 0;
#define EMITG(expr) { if (F >= LO && F < HI) { float _m = (expr);           \
        if (F & 1) sM[wb + (F >> 1)] = pack2(pend, _m); else pend = _m; }   \
        F++; }
    #pragma unroll
    for (int i = 0; i < 9; i++)
        #pragma unroll
        for (int j = i; j < 9; j++)
            #pragma unroll
            for (int k = j; k < 9; k++)
                EMITG(xv[i] * xv[j] * xv[k])
    #pragma unroll
    for (int i = 0; i < 9; i++)
        #pragma unroll
        for (int j = i; j < 9; j++)
            EMITG(xv[i] * xv[j])
    #pragma unroll
    for (int i = 0; i < 9; i++)
        EMITG(xv[i])
    #pragma unroll
    for (int z = 0; z < 5; z++)   // zero-pad f 219..223
        EMITG(0.f)
#undef EMITG
}

__global__ void zero_cursors_kernel(int* cursors) {
    if (threadIdx.x < 16) cursors[threadIdx.x] = 0;
}

// Atomic append bucketing. List ORDER is nondeterministic, but each node's
// result is a fixed-order dot product independent of its list slot, so
// d_out is bit-deterministic.
__global__ void bucket_kernel(const int* __restrict__ indices,
                              int* __restrict__ cursors,
                              int* __restrict__ lists) {
    int b = blockIdx.x * blockDim.x + threadIdx.x;
    if (b < NN) {
        int e = indices[b];
        int slot = atomicAdd(&cursors[e], 1);
        lists[e * NN + slot] = b;
    }
}

// Symmetrize u3 over (i,j,k) and u2 over (i,j) into monomial-indexed tensors.
__global__ void sym_u_kernel(const float* __restrict__ u3,
                             const float* __restrict__ u2,
                             float* __restrict__ su3,
                             float* __restrict__ su2) {
    int gid = blockIdx.x * blockDim.x + threadIdx.x;
    if (gid < F3 * PP3) {
        int t = gid / PP3, p = gid % PP3;
        int I0 = 0, J0 = 0, K0 = 0;
        {
            int rem = t;
            bool found = false;
            for (int i = 0; i < 9 && !found; i++)
                for (int j = i; j < 9 && !found; j++) {
                    int cnt = 9 - j;
                    if (rem < cnt) { I0 = i; J0 = j; K0 = j + rem; found = true; }
                    else rem -= cnt;
                }
        }
        int a[3] = {I0, J0, K0};
        const int ord[6][3] = {{0,1,2},{0,2,1},{1,0,2},{1,2,0},{2,0,1},{2,1,0}};
        int codes[6], pi[6], pj[6], pk[6];
        int np = 0;
        for (int q = 0; q < 6; q++) {
            int ii = a[ord[q][0]], jj = a[ord[q][1]], kk = a[ord[q][2]];
            int code = (ii * 9 + jj) * 9 + kk;
            bool seen = false;
            for (int r = 0; r < np; r++) if (codes[r] == code) seen = true;
            if (!seen) { codes[np] = code; pi[np] = ii; pj[np] = jj; pk[np] = kk; np++; }
        }
        for (int d = 0; d < 9; d++) {
            float s = 0.f;
            for (int q = 0; q < np; q++)
                s += u3[((((d * 9 + pi[q]) * 9 + pj[q]) * 9 + pk[q]) * PP3) + p];
            su3[(t * PP3 + p) * 9 + d] = s;
        }
    } else if (gid < F3 * PP3 + F2 * PP2) {
        int r = gid - F3 * PP3;
        int t = r / PP2, p = r % PP2;
        int I0 = 0, J0 = 0;
        {
            int rem = t;
            bool found = false;
            for (int i = 0; i < 9 && !found; i++) {
                int cnt = 9 - i;
                if (rem < cnt) { I0 = i; J0 = i + rem; found = true; }
                else rem -= cnt;
            }
        }
        for (int d = 0; d < 9; d++) {
            float s = u2[(((d * 9 + I0) * 9 + J0) * PP2) + p];
            if (I0 != J0) s += u2[(((d * 9 + J0) * 9 + I0) * PP2) + p];
            su2[(t * PP2 + p) * 9 + d] = s;
        }
    }
}

// Precompute per-(e,c) f16 weight image, layout [d (16, col)][f (224, K)].
// One thread per f: su3 rows read as float4 vector loads, w-weights
// block-uniform (SGPR), output staged in LDS, copied out coalesced.
__global__ __launch_bounds__(256) void wprep16_kernel(
    const float* __restrict__ su3,
    const float* __restrict__ su2,
    const float* __restrict__ u1,
    const float* __restrict__ w3,
    const float* __restrict__ w2,
    const float* __restrict__ w1,
    unsigned* __restrict__ Wg16)
{
    const int c = blockIdx.x;
    const int e = blockIdx.y;
    const int tid = threadIdx.x;

    __shared__ unsigned short sImg[16 * FPAD];   // 7 KB f16 image [d][f]
    unsigned* sImgW = reinterpret_cast<unsigned*>(sImg);
    for (int q = tid; q < 16 * FPAD / 2; q += 256) sImgW[q] = 0u;
    __syncthreads();

    if (tid < FTOT) {
        float acc[9];
        #pragma unroll
        for (int d = 0; d < 9; d++) acc[d] = 0.f;

        if (tid < F3) {
            const float* sp = su3 + (size_t)tid * PP3 * 9;
            #pragma unroll
            for (int p = 0; p < PP3; p++) {
                const float wv = w3[(e * PP3 + p) * CC + c];     // uniform -> SGPR
                const float4 a = *reinterpret_cast<const float4*>(sp + p * 9);
                const float4 b = *reinterpret_cast<const float4*>(sp + p * 9 + 4);
                const float g = sp[p * 9 + 8];
                acc[0] += wv * a.x; acc[1] += wv * a.y; acc[2] += wv * a.z; acc[3] += wv * a.w;
                acc[4] += wv * b.x; acc[5] += wv * b.y; acc[6] += wv * b.z; acc[7] += wv * b.w;
                acc[8] += wv * g;
            }
        } else if (tid < F3 + F2) {
            const float* sp = su2 + (size_t)(tid - F3) * PP2 * 9;
            #pragma unroll
            for (int p = 0; p < PP2; p++) {
                const float wv = w2[(e * PP2 + p) * CC + c];
                const float4 a = *reinterpret_cast<const float4*>(sp + p * 9);
                const float4 b = *reinterpret_cast<const float4*>(sp + p * 9 + 4);
                const float g = sp[p * 9 + 8];
                acc[0] += wv * a.x; acc[1] += wv * a.y; acc[2] += wv * a.z; acc[3] += wv * a.w;
                acc[4] += wv * b.x; acc[5] += wv * b.y; acc[6] += wv * b.z; acc[7] += wv * b.w;
                acc[8] += wv * g;
            }
        } else {
            const int i = tid - F3 - F2;
            #pragma unroll
            for (int p = 0; p < PP1; p++) {
                const float wv = w1[(e * PP1 + p) * CC + c];
                #pragma unroll
                for (int d = 0; d < 9; d++)
                    acc[d] += wv * u1[(d * 9 + i) * PP1 + p];
            }
        }
        #pragma unroll
        for (int d = 0; d < 9; d++)
            sImg[d * FPAD + tid] = h16(acc[d]);
    }
    __syncthreads();

    unsigned* dst = Wg16 + (size_t)(e * CC + c) * (16 * FPAD / 2);
    for (int q = tid; q < 16 * FPAD / 2; q += 256) dst[q] = sImgW[q];
}

// Main MFMA kernel: grid (C, E), 256 threads (4 waves), 64 nodes/iter.
// Phase 1: ALL 4 waves compute monomials — wave w computes static quarter
//          [w*56, (w+1)*56) of node (tid&63)'s 224-entry stream (wave-uniform
//          branch). Next iteration's x-rows are prefetched at phase-1 top.
// Phase 2: each wave runs ONE 16x16x32 f16 MFMA tile (7 K-tiles), writes
//          D[node][d] with the verified C/D layout.
__global__ __launch_bounds__(256, 5) void symcon_mfma_kernel(
    const float* __restrict__ x,
    const unsigned short* __restrict__ Wg16,
    const int* __restrict__ cursors,
    const int* __restrict__ lists,
    float* __restrict__ out)
{
    const int c = blockIdx.x;
    const int e = blockIdx.y;
    const int tid = threadIdx.x;
    const int lane = tid & 63;
    const int wid = tid >> 6;
    const int nl = tid & 63;       // node slot within iter (same for all waves)

    __shared__ __align__(16) unsigned sM[NODES_PER_ITER * MROW];
    __shared__ int sNid[NODES_PER_ITER];

    // B fragments: lane holds B[k = t*32 + (lane>>4)*8 + j][col = lane&15]
    const int bcol = lane & 15;
    const int bg = lane >> 4;
    f16x8 bfrag[NKT];
    {
        const unsigned short* wp = Wg16 + (size_t)(e * CC + c) * (16 * FPAD);
        #pragma unroll
        for (int t = 0; t < NKT; t++)
            bfrag[t] = *reinterpret_cast<const f16x8*>(wp + bcol * FPAD + t * 32 + bg * 8);
    }

    const int cnt = cursors[e];

    // prologue: load iter-0 x row
    int nb;
    float xv[9];
    {
        const bool valid = (nl < cnt);
        nb = valid ? lists[e * NN + nl] : 0;
        const float* xr = x + ((size_t)nb * CC + c) * II;
        #pragma unroll
        for (int q = 0; q < 9; q++) xv[q] = valid ? xr[q] : 0.f;
    }

    for (int base = 0; base < cnt; base += NODES_PER_ITER) {
        // ---- prefetch next iter's x row (hidden under phase1+phase2) ----
        int nbn = 0;
        float xn[9];
        {
            const int n = base + NODES_PER_ITER + nl;
            const bool valid = (n < cnt);
            nbn = valid ? lists[e * NN + n] : 0;
            const float* xr = x + ((size_t)nbn * CC + c) * II;
            #pragma unroll
            for (int q = 0; q < 9; q++) xn[q] = valid ? xr[q] : 0.f;
        }

        // ---- phase 1: monomials (all waves, static quarter each) ----
        const int wb = nl * MROW;
        if (wid == 0)      emit_mono<0, 56>(xv, sM, wb);
        else if (wid == 1) emit_mono<56, 112>(xv, sM, wb);
        else if (wid == 2) emit_mono<112, 168>(xv, sM, wb);
        else               emit_mono<168, 224>(xv, sM, wb);
        if (wid == 0) sNid[nl] = nb;
        __syncthreads();

        // ---- phase 2: MFMA (1 tile per wave) ----
        {
            const int arow = wid * 16 + (lane & 15);
            const int abase = arow * MROW + bg * 4;
            f32x4 acc = {0.f, 0.f, 0.f, 0.f};
            #pragma unroll
            for (int t = 0; t < NKT; t++) {
                const f16x8 af = *reinterpret_cast<const f16x8*>(&sM[abase + t * 16]);
                acc = __builtin_amdgcn_mfma_f32_16x16x32_f16(af, bfrag[t], acc, 0, 0, 0);
            }
            // C/D: col = lane&15 (= output d), row = (lane>>4)*4 + p (= node slot)
            if (bcol < 9) {
                #pragma unroll
                for (int p = 0; p < 4; p++) {
                    const int s = wid * 16 + bg * 4 + p;
                    if (base + s < cnt) {
                        const int b = sNid[s];
                        out[((size_t)b * CC + c) * DD + bcol] = acc[p];
                    }
                }
            }
        }
        __syncthreads();

        // rotate prefetched registers
        nb = nbn;
        #pragma unroll
        for (int q = 0; q < 9; q++) xv[q] = xn[q];
    }
}

extern "C" void kernel_launch(void* const* d_in, const int* in_sizes, int n_in,
                              void* d_out, int out_size, void* d_ws, size_t ws_size,
                              hipStream_t stream) {
    const float* x   = (const float*)d_in[0];
    const int* indices = (const int*)d_in[1];
    const float* u3  = (const float*)d_in[2];
    const float* u2  = (const float*)d_in[3];
    const float* u1  = (const float*)d_in[4];
    const float* w3  = (const float*)d_in[5];
    const float* w2  = (const float*)d_in[6];
    const float* w1  = (const float*)d_in[7];
    float* out = (float*)d_out;

    char* ws = (char*)d_ws;
    float* su3 = (float*)(ws + SU3_OFF);
    float* su2 = (float*)(ws + SU2_OFF);
    int* cursors = (int*)(ws + CUR_OFF);
    int* lists = (int*)(ws + LIST_OFF);
    unsigned* Wg16 = (unsigned*)(ws + WG16_OFF);

    hipLaunchKernelGGL(zero_cursors_kernel, dim3(1), dim3(64), 0, stream, cursors);
    hipLaunchKernelGGL(bucket_kernel, dim3((NN + 255) / 256), dim3(256), 0, stream,
                       indices, cursors, lists);
    hipLaunchKernelGGL(sym_u_kernel, dim3((F3 * PP3 + F2 * PP2 + 255) / 256), dim3(256),
                       0, stream, u3, u2, su3, su2);
    hipLaunchKernelGGL(wprep16_kernel, dim3(CC, EE), dim3(256), 0, stream,
                       su3, su2, u1, w3, w2, w1, Wg16);
    hipLaunchKernelGGL(symcon_mfma_kernel, dim3(CC, EE), dim3(256), 0, stream,
                       x, (const unsigned short*)Wg16, cursors, lists, out);
}